// Round 13
// baseline (204.480 us; speedup 1.0000x reference)
//
#include <hip/hip_runtime.h>
#include <math.h>

#define DIN   128
#define DOUT  64
#define NHEAD 4
#define HD    16

typedef __attribute__((ext_vector_type(8))) short bf16x8;
typedef __attribute__((ext_vector_type(8))) unsigned short u16x8;
typedef __attribute__((ext_vector_type(4))) float f32x4;

__device__ __forceinline__ unsigned short f2bf(float f) {
    union { float f; unsigned u; } v; v.f = f;
    unsigned r = v.u + 0x7FFF + ((v.u >> 16) & 1);   // round-to-nearest-even
    return (unsigned short)(r >> 16);
}
__device__ __forceinline__ float bf2f(unsigned short s) {
    union { unsigned u; float f; } v; v.u = ((unsigned)s) << 16; return v.f;
}

// ---------------- init: wT bf16 (blocks 0..95) + zero degi/counter ----------
__global__ __launch_bounds__(256)
void k_init(const float* __restrict__ Ws, const float* __restrict__ Wd,
            const float* __restrict__ Wl, short* __restrict__ wT,
            int* __restrict__ degi, int* __restrict__ counter, int N) {
    const int bid = blockIdx.x, tid = threadIdx.x;
    if (bid < 96) {
        const int idx = bid * 256 + tid;              // 96*256 = 24576 = 192*128
        const int n = idx >> 7, k = idx & 127;
        float v;
        if (n < 64)       v = Ws[k * DOUT + n];
        else if (n < 128) v = Wd[k * DOUT + (n - 64)];
        else              v = Wl[k * DOUT + (n - 128)];
        wT[idx] = (short)f2bf(v);
        if (bid == 0 && tid == 0) *counter = 0;
        return;
    }
    const int i = (bid - 96) * 256 + tid;
    if (i < N) degi[i] = 0;
}

// ---------------- fused: node_proj (even blocks) + hist (odd blocks) --------
// proj role: 1 wave = 16 nodes, MFMA GEMM (exact R12 numerics).
// hist role: 64 threads x 4 edges, atomic rank.
// packed_bf[node]: 16 chunks of 8 shorts; chunk cc = head*4+q:
//   slots 0-3 = xs dims head*16+q*4..+3 ; slots 4-7 = h same dims.
__global__ __launch_bounds__(64)
void k_proj_hist(const float* __restrict__ x, const short* __restrict__ wT,
                 const float* __restrict__ bs, const float* __restrict__ bd,
                 const float* __restrict__ bl, const float* __restrict__ Wa,
                 unsigned short* __restrict__ packed_bf,
                 float* __restrict__ xd, float* __restrict__ alpha_s,
                 float* __restrict__ alpha_d, float* __restrict__ h_out, int N,
                 const int* __restrict__ dst, int* __restrict__ degi,
                 int* __restrict__ rank, int E, int NPJ, int NHB) {
    __shared__ short xs[16 * 136];
    const int bid = blockIdx.x, tid = threadIdx.x;

    if (bid & 1) {
        // ---------------- hist role ----------------
        const int hi = bid >> 1;
        if (hi >= NHB) return;
        const int e0 = (hi * 64 + tid) * 4;
        if (e0 + 3 < E) {
            const int4 d = *(const int4*)&dst[e0];
            int4 r;
            r.x = atomicAdd(&degi[d.x], 1);
            r.y = atomicAdd(&degi[d.y], 1);
            r.z = atomicAdd(&degi[d.z], 1);
            r.w = atomicAdd(&degi[d.w], 1);
            *(int4*)&rank[e0] = r;
        } else {
            for (int e = e0; e < E; ++e) rank[e] = atomicAdd(&degi[dst[e]], 1);
        }
        return;
    }

    // ---------------- proj role ----------------
    const int pj = bid >> 1;
    if (pj >= NPJ) return;
    const int lane = tid;
    const int lam = lane & 15, g = lane >> 4;
    const int n0 = pj * 16;

    {
        const int r = lane >> 2, c0 = (lane & 3) * 32;
        const int nn = n0 + r;
#pragma unroll
        for (int j = 0; j < 8; ++j) {
            float4 v = make_float4(0.f, 0.f, 0.f, 0.f);
            if (nn < N) v = ((const float4*)x)[(size_t)nn * 32 + (c0 >> 2) + j];
            short4 h4;
            h4.x = (short)f2bf(v.x); h4.y = (short)f2bf(v.y);
            h4.z = (short)f2bf(v.z); h4.w = (short)f2bf(v.w);
            *(short4*)&xs[r * 136 + c0 + j * 4] = h4;
        }
    }
    __syncthreads();

    bf16x8 afr[4];
#pragma unroll
    for (int ks = 0; ks < 4; ++ks)
        afr[ks] = *(const bf16x8*)&xs[lam * 136 + ks * 32 + g * 8];

    f32x4 acc[12];
#pragma unroll
    for (int c = 0; c < 12; ++c) acc[c] = (f32x4){0.f, 0.f, 0.f, 0.f};

#pragma unroll
    for (int c = 0; c < 12; ++c) {
#pragma unroll
        for (int ks = 0; ks < 4; ++ks) {
            const bf16x8 b = *(const bf16x8*)&wT[(c * 16 + lam) * 128 + ks * 32 + g * 8];
            acc[c] = __builtin_amdgcn_mfma_f32_16x16x32_bf16(afr[ks], b, acc[c], 0, 0, 0);
        }
    }

    float bsv[4], bdv[4], blv[4];
#pragma unroll
    for (int c = 0; c < 4; ++c) {
        bsv[c] = bs[c * 16 + lam];
        bdv[c] = bd[c * 16 + lam];
        blv[c] = bl[c * 16 + lam];
    }
    const float waS = Wa[lam], waD = Wa[16 + lam];
    const int cc_base = (lam >> 2), t_sl = lam & 3;

#pragma unroll
    for (int i = 0; i < 4; ++i) {
        const int node = n0 + g * 4 + i;
        float xsv[4], xdv[4], hv[4];
#pragma unroll
        for (int c = 0; c < 4; ++c) {
            xsv[c] = acc[c][i]     + bsv[c];
            xdv[c] = acc[4 + c][i] + bdv[c];
            hv[c]  = acc[8 + c][i] + blv[c];
        }
        float p0 = hv[0] * waS, p1 = hv[1] * waS, p2 = hv[2] * waS, p3 = hv[3] * waS;
        float q0 = hv[0] * waD, q1 = hv[1] * waD, q2 = hv[2] * waD, q3 = hv[3] * waD;
#pragma unroll
        for (int off = 1; off < 16; off <<= 1) {
            p0 += __shfl_xor(p0, off); p1 += __shfl_xor(p1, off);
            p2 += __shfl_xor(p2, off); p3 += __shfl_xor(p3, off);
            q0 += __shfl_xor(q0, off); q1 += __shfl_xor(q1, off);
            q2 += __shfl_xor(q2, off); q3 += __shfl_xor(q3, off);
        }
        if (node < N) {
            const size_t rowb = (size_t)node * 128;
#pragma unroll
            for (int c = 0; c < 4; ++c) {
                const int cc = c * 4 + cc_base;
                packed_bf[rowb + cc * 8 + t_sl]     = f2bf(xsv[c]);
                packed_bf[rowb + cc * 8 + 4 + t_sl] = f2bf(hv[c]);
                xd   [(size_t)node * DOUT + c * 16 + lam] = xdv[c];
                h_out[(size_t)node * DOUT + c * 16 + lam] = hv[c];
            }
            if (lam == 0) {
                *(f32x4*)&alpha_s[(size_t)node * NHEAD] = (f32x4){p0, p1, p2, p3};
                *(f32x4*)&alpha_d[(size_t)node * NHEAD] = (f32x4){q0, q1, q2, q3};
            }
        }
    }
}

// ---------------- single-kernel scan (last-block finish, atomics-only) ------
__global__ __launch_bounds__(1024)
void k_scan(const int* __restrict__ degi, int* __restrict__ excl,
            int* __restrict__ bsum, int* __restrict__ boff,
            int* __restrict__ total, int* __restrict__ counter, int N, int NB) {
    __shared__ int wsum[16];
    __shared__ int amLast;
    const int tid = threadIdx.x, lane = tid & 63, wid = tid >> 6;
    const int i = blockIdx.x * 1024 + tid;
    int v = (i < N) ? degi[i] : 0;
    int incl = v;
#pragma unroll
    for (int off = 1; off < 64; off <<= 1) {
        int t = __shfl_up(incl, off);
        if (lane >= off) incl += t;
    }
    if (lane == 63) wsum[wid] = incl;
    __syncthreads();
    if (tid < 16) {
        int t = wsum[tid];
#pragma unroll
        for (int off = 1; off < 16; off <<= 1) {
            int u = __shfl_up(t, off);
            if (tid >= off) t += u;
        }
        wsum[tid] = t;
    }
    __syncthreads();
    const int base = (wid > 0) ? wsum[wid - 1] : 0;
    if (i < N) excl[i] = incl - v + base;
    if (tid == 1023) atomicExch(&bsum[blockIdx.x], wsum[15]);
    __syncthreads();
    if (tid == 0) {
        __threadfence();
        amLast = (atomicAdd(counter, 1) == NB - 1) ? 1 : 0;
    }
    __syncthreads();
    if (amLast && tid < 64) {
        int b = (tid < NB) ? atomicAdd(&bsum[tid], 0) : 0;
        int inc = b;
#pragma unroll
        for (int off = 1; off < 64; off <<= 1) {
            int t = __shfl_up(inc, off);
            if (lane >= off) inc += t;
        }
        if (tid < NB) boff[tid] = inc - b;
        if (tid == 63) *total = inc;
    }
}

// ---------------- simple vec4 scatter ---------------------------------------
__global__ __launch_bounds__(256)
void k_scatter(const int* __restrict__ src, const int* __restrict__ dst,
               const int* __restrict__ rp_raw, const int* __restrict__ boff,
               const int* __restrict__ rank, int* __restrict__ srcs_sorted, int E) {
    const int e0 = (blockIdx.x * 256 + threadIdx.x) * 4;
    if (e0 + 3 < E) {
        const int4 s = *(const int4*)&src[e0];
        const int4 d = *(const int4*)&dst[e0];
        const int4 r = *(const int4*)&rank[e0];
        srcs_sorted[rp_raw[d.x] + boff[d.x >> 10] + r.x] = s.x;
        srcs_sorted[rp_raw[d.y] + boff[d.y >> 10] + r.y] = s.y;
        srcs_sorted[rp_raw[d.z] + boff[d.z >> 10] + r.z] = s.z;
        srcs_sorted[rp_raw[d.w] + boff[d.w >> 10] + r.w] = s.w;
    } else {
        for (int e = e0; e < E; ++e) {
            const int d = dst[e];
            srcs_sorted[rp_raw[d] + boff[d >> 10] + rank[e]] = src[e];
        }
    }
}

// ---------------- fused per-dst aggregation: unrolled-3, move-free pipeline -
// lane = (g=edge group, hd=lam>>2, q=lam&3); lane owns dims hd*16+q*4..+3.
#define AGG_COMPUTE(PK, AS, VM)                                                \
    {                                                                          \
        const float t0 = __expf(2.f * (bf2f(PK[0]) + xd4.x));                  \
        const float t1 = __expf(2.f * (bf2f(PK[1]) + xd4.y));                  \
        const float t2 = __expf(2.f * (bf2f(PK[2]) + xd4.z));                  \
        const float t3 = __expf(2.f * (bf2f(PK[3]) + xd4.w));                  \
        const float er0 = fmaf(-2.f, __builtin_amdgcn_rcpf(t0 + 1.f), 1.f);    \
        const float er1 = fmaf(-2.f, __builtin_amdgcn_rcpf(t1 + 1.f), 1.f);    \
        const float er2 = fmaf(-2.f, __builtin_amdgcn_rcpf(t2 + 1.f), 1.f);    \
        const float er3 = fmaf(-2.f, __builtin_amdgcn_rcpf(t3 + 1.f), 1.f);    \
        es0 = fmaf(er0, VM, es0); es1 = fmaf(er1, VM, es1);                    \
        es2 = fmaf(er2, VM, es2); es3 = fmaf(er3, VM, es3);                    \
        float p = er0 * wa4.x;                                                 \
        p = fmaf(er1, wa4.y, p);                                               \
        p = fmaf(er2, wa4.z, p);                                               \
        p = fmaf(er3, wa4.w, p);                                               \
        p += __shfl_xor(p, 1);                                                 \
        p += __shfl_xor(p, 2);                                                 \
        float a = AS + adb + p;                                                \
        a = (a >= 0.f) ? a : 0.01f * a;                                        \
        const float w = __expf(a) * VM;                                        \
        s += w;                                                                \
        o0 = fmaf(w, bf2f(PK[4]), o0); o1 = fmaf(w, bf2f(PK[5]), o1);          \
        o2 = fmaf(w, bf2f(PK[6]), o2); o3 = fmaf(w, bf2f(PK[7]), o3);          \
    }

__global__ __launch_bounds__(256, 8)
void k_aggregate(const int* __restrict__ rp_raw, const int* __restrict__ boff,
                 const int* __restrict__ total, const int* __restrict__ srcs,
                 const unsigned short* __restrict__ packed_bf, // [N][128]
                 const float* __restrict__ xd,                 // [N][64]
                 const float* __restrict__ alpha_s, const float* __restrict__ alpha_d,
                 const float* __restrict__ Wa, const float* __restrict__ ba,
                 float* __restrict__ edge_s, float* __restrict__ out, int N) {
    const int lane = threadIdx.x & 63;
    const int n = blockIdx.x * 4 + (threadIdx.x >> 6);
    if (n >= N) return;
    const int g = lane >> 4, lam = lane & 15;
    const int hd = lam >> 2, q = lam & 3;

    const int start = rp_raw[n] + boff[n >> 10];
    const int end = (n + 1 < N) ? (rp_raw[n + 1] + boff[(n + 1) >> 10]) : *total;
    const int deg = end - start;
    const int last = end - 1;

    const float4 xd4 = *(const float4*)&xd[(size_t)n * DOUT + lam * 4];
    const float4 wa4 = *(const float4*)&Wa[32 + q * 4];
    const float adb  = alpha_d[n * NHEAD + hd] + ba[0];

    float es0=0.f,es1=0.f,es2=0.f,es3=0.f;
    float o0=0.f,o1=0.f,o2=0.f,o3=0.f;
    float s = 0.f;

    const int niter = (deg + 3) >> 2;
    int ebase = start + g;                  // stage-0 compute edge

    float vm0=0.f, vm1=0.f, vm2=0.f;
    u16x8 pk0=(u16x8){0,0,0,0,0,0,0,0}, pk1=pk0, pk2=pk0;
    float as0=0.f, as1=0.f, as2=0.f;
    if (niter > 0) {
        {
            vm0 = (ebase < end) ? 1.f : 0.f;
            const int sn = srcs[min(ebase, last)];
            pk0 = *(const u16x8*)&packed_bf[(size_t)sn * 128 + lam * 8];
            as0 = alpha_s[sn * NHEAD + hd];
        }
        {
            const int e1 = ebase + 4;
            vm1 = (e1 < end) ? 1.f : 0.f;
            const int sn = srcs[min(e1, last)];
            pk1 = *(const u16x8*)&packed_bf[(size_t)sn * 128 + lam * 8];
            as1 = alpha_s[sn * NHEAD + hd];
        }
        {
            const int e2 = ebase + 8;
            vm2 = (e2 < end) ? 1.f : 0.f;
            const int sn = srcs[min(e2, last)];
            pk2 = *(const u16x8*)&packed_bf[(size_t)sn * 128 + lam * 8];
            as2 = alpha_s[sn * NHEAD + hd];
        }
    }

    int it = 0;
    for (; it + 3 <= niter; it += 3, ebase += 12) {
        {   // phase 0: compute iter it, prefetch iter it+3 into stage 0
            float vmn = 0.f, asn = 0.f;
            u16x8 pkn = (u16x8){0,0,0,0,0,0,0,0};
            const int ep = ebase + 12;
            if (it + 3 < niter) {
                vmn = (ep < end) ? 1.f : 0.f;
                const int sn = srcs[min(ep, last)];
                pkn = *(const u16x8*)&packed_bf[(size_t)sn * 128 + lam * 8];
                asn = alpha_s[sn * NHEAD + hd];
            }
            AGG_COMPUTE(pk0, as0, vm0);
            pk0 = pkn; as0 = asn; vm0 = vmn;
        }
        {   // phase 1
            float vmn = 0.f, asn = 0.f;
            u16x8 pkn = (u16x8){0,0,0,0,0,0,0,0};
            const int ep = ebase + 16;
            if (it + 4 < niter) {
                vmn = (ep < end) ? 1.f : 0.f;
                const int sn = srcs[min(ep, last)];
                pkn = *(const u16x8*)&packed_bf[(size_t)sn * 128 + lam * 8];
                asn = alpha_s[sn * NHEAD + hd];
            }
            AGG_COMPUTE(pk1, as1, vm1);
            pk1 = pkn; as1 = asn; vm1 = vmn;
        }
        {   // phase 2
            float vmn = 0.f, asn = 0.f;
            u16x8 pkn = (u16x8){0,0,0,0,0,0,0,0};
            const int ep = ebase + 20;
            if (it + 5 < niter) {
                vmn = (ep < end) ? 1.f : 0.f;
                const int sn = srcs[min(ep, last)];
                pkn = *(const u16x8*)&packed_bf[(size_t)sn * 128 + lam * 8];
                asn = alpha_s[sn * NHEAD + hd];
            }
            AGG_COMPUTE(pk2, as2, vm2);
            pk2 = pkn; as2 = asn; vm2 = vmn;
        }
    }
    // tail: 0..2 remaining iterations (stage data already loaded)
    if (it < niter) {
        AGG_COMPUTE(pk0, as0, vm0);
        ++it;
        if (it < niter) {
            AGG_COMPUTE(pk1, as1, vm1);
        }
    }

    // reduce across the 4 edge groups
#pragma unroll
    for (int off = 16; off < 64; off <<= 1) {
        es0 += __shfl_xor(es0, off); es1 += __shfl_xor(es1, off);
        es2 += __shfl_xor(es2, off); es3 += __shfl_xor(es3, off);
        o0  += __shfl_xor(o0,  off); o1  += __shfl_xor(o1,  off);
        o2  += __shfl_xor(o2,  off); o3  += __shfl_xor(o3,  off);
        s   += __shfl_xor(s,   off);
    }

    if (g == 0) {
        const float inv_s = __builtin_amdgcn_rcpf(fmaxf(s, 1e-38f));
        const float inv_d = __builtin_amdgcn_rcpf(fmaxf((float)deg, 1.0f));
        const size_t od = (size_t)n * DOUT + lam * 4;
        *(f32x4*)&out[od]    = (f32x4){o0 * inv_s, o1 * inv_s, o2 * inv_s, o3 * inv_s};
        *(f32x4*)&edge_s[od] = (f32x4){es0 * inv_d, es1 * inv_d, es2 * inv_d, es3 * inv_d};
    }
}

extern "C" void kernel_launch(void* const* d_in, const int* in_sizes, int n_in,
                              void* d_out, int out_size, void* d_ws, size_t ws_size,
                              hipStream_t stream) {
    const float* x  = (const float*)d_in[0];
    const int*   src= (const int*)  d_in[1];
    const int*   dst= (const int*)  d_in[2];
    const float* Ws = (const float*)d_in[3];
    const float* bs = (const float*)d_in[4];
    const float* Wd = (const float*)d_in[5];
    const float* bd = (const float*)d_in[6];
    const float* Wl = (const float*)d_in[7];
    const float* bl = (const float*)d_in[8];
    const float* Wa = (const float*)d_in[9];
    const float* ba = (const float*)d_in[10];

    const int N = in_sizes[0] / DIN;
    const int E = in_sizes[1];
    const int NB = (N + 1023) / 1024;          // scan blocks (<= 64 required)

    float* out_f = (float*)d_out;
    float* edge_s_out = out_f;                        // chunk 0: [N,64]
    float* out_attn   = out_f + (size_t)N * DOUT;     // chunk 1: [N,64]
    float* h_out      = out_f + 2 * (size_t)N * DOUT; // chunk 2: [N,64]

    char* ws = (char*)d_ws;
    size_t o = 0;
    unsigned short* packed_bf = (unsigned short*)(ws + o); o += (size_t)N * 128 * 2;
    float* xd      = (float*)(ws + o); o += (size_t)N * DOUT * 4;
    float* alpha_s = (float*)(ws + o); o += (size_t)N * NHEAD * 4;
    float* alpha_d = (float*)(ws + o); o += (size_t)N * NHEAD * 4;
    int*   degi    = (int*)  (ws + o); o += (size_t)N * 4;
    int*   counter = (int*)  (ws + o); o += 64;
    int*   rp_raw  = (int*)  (ws + o); o += (size_t)(N + 1) * 4;
    int*   rank    = (int*)  (ws + o); o += (size_t)E * 4;
    int*   srcs    = (int*)  (ws + o); o += (size_t)E * 4;
    int*   bsum    = (int*)  (ws + o); o += 64 * 4;
    int*   boff    = (int*)  (ws + o); o += 64 * 4;
    int*   total   = (int*)  (ws + o); o += 64;
    short* wT      = (short*)(ws + o); o += (size_t)192 * 128 * 2;

    k_init<<<96 + (N + 255) / 256, 256, 0, stream>>>(Ws, Wd, Wl, wT, degi, counter, N);

    const int NPJ = (N + 15) / 16;             // proj blocks (16 nodes each)
    const int NHB = (E + 255) / 256;           // hist blocks (256 edges each)
    const int GC  = 2 * ((NPJ > NHB) ? NPJ : NHB);
    k_proj_hist<<<GC, 64, 0, stream>>>(x, wT, bs, bd, bl, Wa,
                                       packed_bf, xd, alpha_s, alpha_d, h_out, N,
                                       dst, degi, rank, E, NPJ, NHB);

    k_scan<<<NB, 1024, 0, stream>>>(degi, rp_raw, bsum, boff, total, counter, N, NB);

    k_scatter<<<((E + 3) / 4 + 255) / 256, 256, 0, stream>>>(src, dst, rp_raw, boff,
                                                             rank, srcs, E);

    k_aggregate<<<(N + 3) / 4, 256, 0, stream>>>(rp_raw, boff, total, srcs,
                                                 packed_bf, xd,
                                                 alpha_s, alpha_d, Wa, ba,
                                                 edge_s_out, out_attn, N);
}

// Round 14
// 129.925 us; speedup vs baseline: 1.5738x; 1.5738x over previous
//
#include <hip/hip_runtime.h>
#include <math.h>

#define DIN   128
#define DOUT  64
#define NHEAD 4
#define HD    16

typedef __attribute__((ext_vector_type(8))) short bf16x8;
typedef __attribute__((ext_vector_type(8))) unsigned short u16x8;
typedef __attribute__((ext_vector_type(4))) float f32x4;

__device__ __forceinline__ unsigned short f2bf(float f) {
    union { float f; unsigned u; } v; v.f = f;
    unsigned r = v.u + 0x7FFF + ((v.u >> 16) & 1);   // round-to-nearest-even
    return (unsigned short)(r >> 16);
}
__device__ __forceinline__ float bf2f(unsigned short s) {
    union { unsigned u; float f; } v; v.u = ((unsigned)s) << 16; return v.f;
}

// ---------------- init: wT bf16 (blocks 0..95) + zero degi/counter ----------
__global__ __launch_bounds__(256)
void k_init(const float* __restrict__ Ws, const float* __restrict__ Wd,
            const float* __restrict__ Wl, short* __restrict__ wT,
            int* __restrict__ degi, int* __restrict__ counter, int N) {
    const int bid = blockIdx.x, tid = threadIdx.x;
    if (bid < 96) {
        const int idx = bid * 256 + tid;              // 96*256 = 24576 = 192*128
        const int n = idx >> 7, k = idx & 127;
        float v;
        if (n < 64)       v = Ws[k * DOUT + n];
        else if (n < 128) v = Wd[k * DOUT + (n - 64)];
        else              v = Wl[k * DOUT + (n - 128)];
        wT[idx] = (short)f2bf(v);
        if (bid == 0 && tid == 0) *counter = 0;
        return;
    }
    const int i = (bid - 96) * 256 + tid;
    if (i < N) degi[i] = 0;
}

// ---------------- fused: node_proj (even blocks) + hist (odd blocks) --------
// proj role: 1 wave = 16 nodes, MFMA GEMM (exact R12 numerics).
// hist role: 64 threads x 4 edges, atomic rank.
// packed_bf[node]: 16 chunks of 8 shorts; chunk cc = head*4+q:
//   slots 0-3 = xs dims head*16+q*4..+3 ; slots 4-7 = h same dims.
__global__ __launch_bounds__(64)
void k_proj_hist(const float* __restrict__ x, const short* __restrict__ wT,
                 const float* __restrict__ bs, const float* __restrict__ bd,
                 const float* __restrict__ bl, const float* __restrict__ Wa,
                 unsigned short* __restrict__ packed_bf,
                 float* __restrict__ xd, float* __restrict__ alpha_s,
                 float* __restrict__ alpha_d, float* __restrict__ h_out, int N,
                 const int* __restrict__ dst, int* __restrict__ degi,
                 int* __restrict__ rank, int E, int NPJ, int NHB) {
    __shared__ short xs[16 * 136];
    const int bid = blockIdx.x, tid = threadIdx.x;

    if (bid & 1) {
        // ---------------- hist role ----------------
        const int hi = bid >> 1;
        if (hi >= NHB) return;
        const int e0 = (hi * 64 + tid) * 4;
        if (e0 + 3 < E) {
            const int4 d = *(const int4*)&dst[e0];
            int4 r;
            r.x = atomicAdd(&degi[d.x], 1);
            r.y = atomicAdd(&degi[d.y], 1);
            r.z = atomicAdd(&degi[d.z], 1);
            r.w = atomicAdd(&degi[d.w], 1);
            *(int4*)&rank[e0] = r;
        } else {
            for (int e = e0; e < E; ++e) rank[e] = atomicAdd(&degi[dst[e]], 1);
        }
        return;
    }

    // ---------------- proj role ----------------
    const int pj = bid >> 1;
    if (pj >= NPJ) return;
    const int lane = tid;
    const int lam = lane & 15, g = lane >> 4;
    const int n0 = pj * 16;

    {
        const int r = lane >> 2, c0 = (lane & 3) * 32;
        const int nn = n0 + r;
#pragma unroll
        for (int j = 0; j < 8; ++j) {
            float4 v = make_float4(0.f, 0.f, 0.f, 0.f);
            if (nn < N) v = ((const float4*)x)[(size_t)nn * 32 + (c0 >> 2) + j];
            short4 h4;
            h4.x = (short)f2bf(v.x); h4.y = (short)f2bf(v.y);
            h4.z = (short)f2bf(v.z); h4.w = (short)f2bf(v.w);
            *(short4*)&xs[r * 136 + c0 + j * 4] = h4;
        }
    }
    __syncthreads();

    bf16x8 afr[4];
#pragma unroll
    for (int ks = 0; ks < 4; ++ks)
        afr[ks] = *(const bf16x8*)&xs[lam * 136 + ks * 32 + g * 8];

    f32x4 acc[12];
#pragma unroll
    for (int c = 0; c < 12; ++c) acc[c] = (f32x4){0.f, 0.f, 0.f, 0.f};

#pragma unroll
    for (int c = 0; c < 12; ++c) {
#pragma unroll
        for (int ks = 0; ks < 4; ++ks) {
            const bf16x8 b = *(const bf16x8*)&wT[(c * 16 + lam) * 128 + ks * 32 + g * 8];
            acc[c] = __builtin_amdgcn_mfma_f32_16x16x32_bf16(afr[ks], b, acc[c], 0, 0, 0);
        }
    }

    float bsv[4], bdv[4], blv[4];
#pragma unroll
    for (int c = 0; c < 4; ++c) {
        bsv[c] = bs[c * 16 + lam];
        bdv[c] = bd[c * 16 + lam];
        blv[c] = bl[c * 16 + lam];
    }
    const float waS = Wa[lam], waD = Wa[16 + lam];
    const int cc_base = (lam >> 2), t_sl = lam & 3;

#pragma unroll
    for (int i = 0; i < 4; ++i) {
        const int node = n0 + g * 4 + i;
        float xsv[4], xdv[4], hv[4];
#pragma unroll
        for (int c = 0; c < 4; ++c) {
            xsv[c] = acc[c][i]     + bsv[c];
            xdv[c] = acc[4 + c][i] + bdv[c];
            hv[c]  = acc[8 + c][i] + blv[c];
        }
        float p0 = hv[0] * waS, p1 = hv[1] * waS, p2 = hv[2] * waS, p3 = hv[3] * waS;
        float q0 = hv[0] * waD, q1 = hv[1] * waD, q2 = hv[2] * waD, q3 = hv[3] * waD;
#pragma unroll
        for (int off = 1; off < 16; off <<= 1) {
            p0 += __shfl_xor(p0, off); p1 += __shfl_xor(p1, off);
            p2 += __shfl_xor(p2, off); p3 += __shfl_xor(p3, off);
            q0 += __shfl_xor(q0, off); q1 += __shfl_xor(q1, off);
            q2 += __shfl_xor(q2, off); q3 += __shfl_xor(q3, off);
        }
        if (node < N) {
            const size_t rowb = (size_t)node * 128;
#pragma unroll
            for (int c = 0; c < 4; ++c) {
                const int cc = c * 4 + cc_base;
                packed_bf[rowb + cc * 8 + t_sl]     = f2bf(xsv[c]);
                packed_bf[rowb + cc * 8 + 4 + t_sl] = f2bf(hv[c]);
                xd   [(size_t)node * DOUT + c * 16 + lam] = xdv[c];
                h_out[(size_t)node * DOUT + c * 16 + lam] = hv[c];
            }
            if (lam == 0) {
                *(f32x4*)&alpha_s[(size_t)node * NHEAD] = (f32x4){p0, p1, p2, p3};
                *(f32x4*)&alpha_d[(size_t)node * NHEAD] = (f32x4){q0, q1, q2, q3};
            }
        }
    }
}

// ---------------- single-kernel scan (last-block finish, atomics-only) ------
__global__ __launch_bounds__(1024)
void k_scan(const int* __restrict__ degi, int* __restrict__ excl,
            int* __restrict__ bsum, int* __restrict__ boff,
            int* __restrict__ total, int* __restrict__ counter, int N, int NB) {
    __shared__ int wsum[16];
    __shared__ int amLast;
    const int tid = threadIdx.x, lane = tid & 63, wid = tid >> 6;
    const int i = blockIdx.x * 1024 + tid;
    int v = (i < N) ? degi[i] : 0;
    int incl = v;
#pragma unroll
    for (int off = 1; off < 64; off <<= 1) {
        int t = __shfl_up(incl, off);
        if (lane >= off) incl += t;
    }
    if (lane == 63) wsum[wid] = incl;
    __syncthreads();
    if (tid < 16) {
        int t = wsum[tid];
#pragma unroll
        for (int off = 1; off < 16; off <<= 1) {
            int u = __shfl_up(t, off);
            if (tid >= off) t += u;
        }
        wsum[tid] = t;
    }
    __syncthreads();
    const int base = (wid > 0) ? wsum[wid - 1] : 0;
    if (i < N) excl[i] = incl - v + base;
    if (tid == 1023) atomicExch(&bsum[blockIdx.x], wsum[15]);
    __syncthreads();
    if (tid == 0) {
        __threadfence();
        amLast = (atomicAdd(counter, 1) == NB - 1) ? 1 : 0;
    }
    __syncthreads();
    if (amLast && tid < 64) {
        int b = (tid < NB) ? atomicAdd(&bsum[tid], 0) : 0;
        int inc = b;
#pragma unroll
        for (int off = 1; off < 64; off <<= 1) {
            int t = __shfl_up(inc, off);
            if (lane >= off) inc += t;
        }
        if (tid < NB) boff[tid] = inc - b;
        if (tid == 63) *total = inc;
    }
}

// ---------------- simple vec4 scatter ---------------------------------------
__global__ __launch_bounds__(256)
void k_scatter(const int* __restrict__ src, const int* __restrict__ dst,
               const int* __restrict__ rp_raw, const int* __restrict__ boff,
               const int* __restrict__ rank, int* __restrict__ srcs_sorted, int E) {
    const int e0 = (blockIdx.x * 256 + threadIdx.x) * 4;
    if (e0 + 3 < E) {
        const int4 s = *(const int4*)&src[e0];
        const int4 d = *(const int4*)&dst[e0];
        const int4 r = *(const int4*)&rank[e0];
        srcs_sorted[rp_raw[d.x] + boff[d.x >> 10] + r.x] = s.x;
        srcs_sorted[rp_raw[d.y] + boff[d.y >> 10] + r.y] = s.y;
        srcs_sorted[rp_raw[d.z] + boff[d.z >> 10] + r.z] = s.z;
        srcs_sorted[rp_raw[d.w] + boff[d.w >> 10] + r.w] = s.w;
    } else {
        for (int e = e0; e < E; ++e) {
            const int d = dst[e];
            srcs_sorted[rp_raw[d] + boff[d >> 10] + rank[e]] = src[e];
        }
    }
}

// ---------------- fused per-dst aggregation: 1 node/wave, 4 edges/iter ------
// lane = (g=edge group, hd=lam>>2, q=lam&3); lane owns dims hd*16+q*4..+3.
// prefetch distance 3 (rotating pipeline, R12-verbatim: 32 VGPR, no spill).
__global__ __launch_bounds__(256, 8)
void k_aggregate(const int* __restrict__ rp_raw, const int* __restrict__ boff,
                 const int* __restrict__ total, const int* __restrict__ srcs,
                 const unsigned short* __restrict__ packed_bf, // [N][128]
                 const float* __restrict__ xd,                 // [N][64]
                 const float* __restrict__ alpha_s, const float* __restrict__ alpha_d,
                 const float* __restrict__ Wa, const float* __restrict__ ba,
                 float* __restrict__ edge_s, float* __restrict__ out, int N) {
    const int lane = threadIdx.x & 63;
    const int n = blockIdx.x * 4 + (threadIdx.x >> 6);
    if (n >= N) return;
    const int g = lane >> 4, lam = lane & 15;
    const int hd = lam >> 2, q = lam & 3;

    const int start = rp_raw[n] + boff[n >> 10];
    const int end = (n + 1 < N) ? (rp_raw[n + 1] + boff[(n + 1) >> 10]) : *total;
    const int deg = end - start;
    const int last = end - 1;

    const float4 xd4 = *(const float4*)&xd[(size_t)n * DOUT + lam * 4];
    const float4 wa4 = *(const float4*)&Wa[32 + q * 4];
    const float adb  = alpha_d[n * NHEAD + hd] + ba[0];

    float es0=0.f,es1=0.f,es2=0.f,es3=0.f;
    float o0=0.f,o1=0.f,o2=0.f,o3=0.f;
    float s = 0.f;

    const int niter = (deg + 3) >> 2;
    int e = start + g;

    float vm0=0.f, vm1=0.f, vm2=0.f;
    u16x8 pk0=(u16x8){0,0,0,0,0,0,0,0}, pk1=pk0, pk2=pk0;
    float as0=0.f, as1=0.f, as2=0.f;
    if (niter > 0) {
        {
            vm0 = (e < end) ? 1.f : 0.f;
            const int sn = srcs[min(e, last)];
            pk0 = *(const u16x8*)&packed_bf[(size_t)sn * 128 + lam * 8];
            as0 = alpha_s[sn * NHEAD + hd];
        }
        {
            const int e1 = e + 4;
            vm1 = (e1 < end) ? 1.f : 0.f;
            const int sn = srcs[min(e1, last)];
            pk1 = *(const u16x8*)&packed_bf[(size_t)sn * 128 + lam * 8];
            as1 = alpha_s[sn * NHEAD + hd];
        }
        {
            const int e2 = e + 8;
            vm2 = (e2 < end) ? 1.f : 0.f;
            const int sn = srcs[min(e2, last)];
            pk2 = *(const u16x8*)&packed_bf[(size_t)sn * 128 + lam * 8];
            as2 = alpha_s[sn * NHEAD + hd];
        }
    }

    for (int it = 0; it < niter; ++it) {
        float vmn = 0.f, asn = 0.f;
        u16x8 pkn = (u16x8){0,0,0,0,0,0,0,0};
        const int e3 = e + 12;
        if (it + 3 < niter) {
            vmn = (e3 < end) ? 1.f : 0.f;
            const int sn = srcs[min(e3, last)];
            pkn = *(const u16x8*)&packed_bf[(size_t)sn * 128 + lam * 8];
            asn = alpha_s[sn * NHEAD + hd];
        }

        const float t0 = __expf(2.f * (bf2f(pk0[0]) + xd4.x));
        const float t1 = __expf(2.f * (bf2f(pk0[1]) + xd4.y));
        const float t2 = __expf(2.f * (bf2f(pk0[2]) + xd4.z));
        const float t3 = __expf(2.f * (bf2f(pk0[3]) + xd4.w));
        const float er0 = fmaf(-2.f, __builtin_amdgcn_rcpf(t0 + 1.f), 1.f);
        const float er1 = fmaf(-2.f, __builtin_amdgcn_rcpf(t1 + 1.f), 1.f);
        const float er2 = fmaf(-2.f, __builtin_amdgcn_rcpf(t2 + 1.f), 1.f);
        const float er3 = fmaf(-2.f, __builtin_amdgcn_rcpf(t3 + 1.f), 1.f);
        es0 = fmaf(er0, vm0, es0); es1 = fmaf(er1, vm0, es1);
        es2 = fmaf(er2, vm0, es2); es3 = fmaf(er3, vm0, es3);

        float p = er0 * wa4.x;
        p = fmaf(er1, wa4.y, p);
        p = fmaf(er2, wa4.z, p);
        p = fmaf(er3, wa4.w, p);
        p += __shfl_xor(p, 1);
        p += __shfl_xor(p, 2);

        float a = as0 + adb + p;
        a = (a >= 0.f) ? a : 0.01f * a;            // leaky relu
        const float w = __expf(a) * vm0;
        s += w;
        o0 = fmaf(w, bf2f(pk0[4]), o0); o1 = fmaf(w, bf2f(pk0[5]), o1);
        o2 = fmaf(w, bf2f(pk0[6]), o2); o3 = fmaf(w, bf2f(pk0[7]), o3);

        vm0 = vm1; pk0 = pk1; as0 = as1;
        vm1 = vm2; pk1 = pk2; as1 = as2;
        vm2 = vmn; pk2 = pkn; as2 = asn;
        e += 4;
    }

#pragma unroll
    for (int off = 16; off < 64; off <<= 1) {
        es0 += __shfl_xor(es0, off); es1 += __shfl_xor(es1, off);
        es2 += __shfl_xor(es2, off); es3 += __shfl_xor(es3, off);
        o0  += __shfl_xor(o0,  off); o1  += __shfl_xor(o1,  off);
        o2  += __shfl_xor(o2,  off); o3  += __shfl_xor(o3,  off);
        s   += __shfl_xor(s,   off);
    }

    if (g == 0) {
        const float inv_s = __builtin_amdgcn_rcpf(fmaxf(s, 1e-38f));
        const float inv_d = __builtin_amdgcn_rcpf(fmaxf((float)deg, 1.0f));
        const size_t od = (size_t)n * DOUT + lam * 4;
        *(f32x4*)&out[od]    = (f32x4){o0 * inv_s, o1 * inv_s, o2 * inv_s, o3 * inv_s};
        *(f32x4*)&edge_s[od] = (f32x4){es0 * inv_d, es1 * inv_d, es2 * inv_d, es3 * inv_d};
    }
}

extern "C" void kernel_launch(void* const* d_in, const int* in_sizes, int n_in,
                              void* d_out, int out_size, void* d_ws, size_t ws_size,
                              hipStream_t stream) {
    const float* x  = (const float*)d_in[0];
    const int*   src= (const int*)  d_in[1];
    const int*   dst= (const int*)  d_in[2];
    const float* Ws = (const float*)d_in[3];
    const float* bs = (const float*)d_in[4];
    const float* Wd = (const float*)d_in[5];
    const float* bd = (const float*)d_in[6];
    const float* Wl = (const float*)d_in[7];
    const float* bl = (const float*)d_in[8];
    const float* Wa = (const float*)d_in[9];
    const float* ba = (const float*)d_in[10];

    const int N = in_sizes[0] / DIN;
    const int E = in_sizes[1];
    const int NB = (N + 1023) / 1024;          // scan blocks (<= 64 required)

    float* out_f = (float*)d_out;
    float* edge_s_out = out_f;                        // chunk 0: [N,64]
    float* out_attn   = out_f + (size_t)N * DOUT;     // chunk 1: [N,64]
    float* h_out      = out_f + 2 * (size_t)N * DOUT; // chunk 2: [N,64]

    char* ws = (char*)d_ws;
    size_t o = 0;
    unsigned short* packed_bf = (unsigned short*)(ws + o); o += (size_t)N * 128 * 2;
    float* xd      = (float*)(ws + o); o += (size_t)N * DOUT * 4;
    float* alpha_s = (float*)(ws + o); o += (size_t)N * NHEAD * 4;
    float* alpha_d = (float*)(ws + o); o += (size_t)N * NHEAD * 4;
    int*   degi    = (int*)  (ws + o); o += (size_t)N * 4;
    int*   counter = (int*)  (ws + o); o += 64;
    int*   rp_raw  = (int*)  (ws + o); o += (size_t)(N + 1) * 4;
    int*   rank    = (int*)  (ws + o); o += (size_t)E * 4;
    int*   srcs    = (int*)  (ws + o); o += (size_t)E * 4;
    int*   bsum    = (int*)  (ws + o); o += 64 * 4;
    int*   boff    = (int*)  (ws + o); o += 64 * 4;
    int*   total   = (int*)  (ws + o); o += 64;
    short* wT      = (short*)(ws + o); o += (size_t)192 * 128 * 2;

    k_init<<<96 + (N + 255) / 256, 256, 0, stream>>>(Ws, Wd, Wl, wT, degi, counter, N);

    const int NPJ = (N + 15) / 16;             // proj blocks (16 nodes each)
    const int NHB = (E + 255) / 256;           // hist blocks (256 edges each)
    const int GC  = 2 * ((NPJ > NHB) ? NPJ : NHB);
    k_proj_hist<<<GC, 64, 0, stream>>>(x, wT, bs, bd, bl, Wa,
                                       packed_bf, xd, alpha_s, alpha_d, h_out, N,
                                       dst, degi, rank, E, NPJ, NHB);

    k_scan<<<NB, 1024, 0, stream>>>(degi, rp_raw, bsum, boff, total, counter, N, NB);

    k_scatter<<<((E + 3) / 4 + 255) / 256, 256, 0, stream>>>(src, dst, rp_raw, boff,
                                                             rank, srcs, E);

    k_aggregate<<<(N + 3) / 4, 256, 0, stream>>>(rp_raw, boff, total, srcs,
                                                 packed_bf, xd,
                                                 alpha_s, alpha_d, Wa, ba,
                                                 edge_s_out, out_attn, N);
}